// Round 12
// baseline (200.059 us; speedup 1.0000x reference)
//
#include <hip/hip_runtime.h>
#include <math.h>

// SIREN forward: coords [N,3] -> first(3->5,sin) -> 256 x hidden(5->5,sin) -> final(5->1)
// Output layout: d_out[0..N) = net output, d_out[N..4N) = coords passthrough.
//
// Round 12: P=8 (1 wave/SIMD) — endpoint test of the contention theory.
//  - Ledger R2-R11: all variants 152-163us; idle fell monotonically with wave
//    count (8w:25% -> 4w:22% -> 2w:19%). If idle = cross-wave contention
//    (K$ lines / issue arbiter), 1 wave/SIMD should drop it further; if idle
//    stays ~19%, it's per-wave structural and R4-class is the ceiling.
//  - v_sin (hw sin) empirically beats all poly variants (VOP3 3-src reads
//    appear to cap sustained VALU at ~2/3 nominal, cf. m07's 103/157 TF).
//  - s_load weights (R4 path): LDS and dbuf variants were neutral-to-worse.
//  - 40 independent fma->sin chains/wave; ~1040cyc/layer gives the compiler
//    room to prefetch next layer's s_loads entirely within the wave.
//  - Weights prescaled by 30/(2pi) in d_ws: sin in revolution units via
//    __builtin_amdgcn_sinf, |z| <= ~7.6 rev (domain +-256), no fract needed.

#define SIREN_HID 5
#define SIREN_NLAYERS 256
// 30 / (2*pi)
#define SIREN_REV 4.774648292756860f
#define PTS 8

// ---------------- prep: scale weights into revolution units ----------------
// d_ws layout (floats):
//   [0 .. 8192)        hidden layers: layer l at l*32: w[0..24], b[25..29], pad
//   [8192 .. 8207)     first layer W (5x3, row-major), scaled
//   [8207 .. 8212)     first layer b, scaled
__global__ __launch_bounds__(256)
void siren_prep(const float* __restrict__ Wf, const float* __restrict__ bf,
                const float* __restrict__ Wh, const float* __restrict__ bh,
                float* __restrict__ ws)
{
    int t = blockIdx.x * blockDim.x + threadIdx.x;
    const int total = SIREN_NLAYERS * 32;
    for (int idx = t; idx < total; idx += gridDim.x * blockDim.x) {
        int l = idx >> 5;
        int k = idx & 31;
        float v = 0.0f;
        if (k < 25)      v = Wh[l * 25 + k] * SIREN_REV;
        else if (k < 30) v = bh[l * 5 + (k - 25)] * SIREN_REV;
        ws[idx] = v;
    }
    if (t < 15) ws[total + t]      = Wf[t] * SIREN_REV;
    if (t < 5)  ws[total + 15 + t] = bf[t] * SIREN_REV;
}

// ---------------- main: 8 points per thread, hw sin, s_load weights ---------
__global__ __launch_bounds__(256, 1)
void siren_fwd12(const float* __restrict__ coords,
                 const float* __restrict__ lw,    // [256][32] scaled hidden w/b
                 const float* __restrict__ fw,    // [20] scaled first w(15)+b(5)
                 const float* __restrict__ Wfin,  // [1][5] (unscaled)
                 const float* __restrict__ bfin,  // [1]
                 float* __restrict__ out, int N)
{
    int i = blockIdx.x * blockDim.x + threadIdx.x;
    const int M = N / PTS;                // groups of 8 points
    i = (i < M) ? i : (M - 1);            // uniform clamp, no divergent return

    // 8 adjacent points: 96B contiguous load as 6x float4
    const float4* cp4 = (const float4*)(coords + 3 * PTS * i);
    float4 q[6];
#pragma unroll
    for (int k = 0; k < 6; ++k) q[k] = cp4[k];

    // unpack to c[p][d] (all constant indices after unroll -> registers)
    float cc[24];
#pragma unroll
    for (int k = 0; k < 6; ++k) {
        cc[4 * k + 0] = q[k].x;
        cc[4 * k + 1] = q[k].y;
        cc[4 * k + 2] = q[k].z;
        cc[4 * k + 3] = q[k].w;
    }

    float h[PTS][SIREN_HID];

    // first layer (revolution units): h_j = sin_rev(c . w[j,:] + b[j])
#pragma unroll
    for (int p = 0; p < PTS; ++p) {
#pragma unroll
        for (int j = 0; j < SIREN_HID; ++j) {
            float z = fmaf(cc[3 * p + 2], fw[3 * j + 2],
                      fmaf(cc[3 * p + 1], fw[3 * j + 1],
                      fmaf(cc[3 * p + 0], fw[3 * j + 0], fw[15 + j])));
            h[p][j] = __builtin_amdgcn_sinf(z);
        }
    }

    // 256 hidden layers, weights via uniform scalar loads (s_load, K$)
#pragma unroll 2
    for (int l = 0; l < SIREN_NLAYERS; ++l) {
        const float* w = lw + l * 32;
        float b0 = w[25], b1 = w[26], b2 = w[27], b3 = w[28], b4 = w[29];
        float z[PTS][SIREN_HID];
#pragma unroll
        for (int p = 0; p < PTS; ++p) {
            z[p][0] = fmaf(h[p][4], w[ 4], fmaf(h[p][3], w[ 3], fmaf(h[p][2], w[ 2], fmaf(h[p][1], w[ 1], fmaf(h[p][0], w[ 0], b0)))));
            z[p][1] = fmaf(h[p][4], w[ 9], fmaf(h[p][3], w[ 8], fmaf(h[p][2], w[ 7], fmaf(h[p][1], w[ 6], fmaf(h[p][0], w[ 5], b1)))));
            z[p][2] = fmaf(h[p][4], w[14], fmaf(h[p][3], w[13], fmaf(h[p][2], w[12], fmaf(h[p][1], w[11], fmaf(h[p][0], w[10], b2)))));
            z[p][3] = fmaf(h[p][4], w[19], fmaf(h[p][3], w[18], fmaf(h[p][2], w[17], fmaf(h[p][1], w[16], fmaf(h[p][0], w[15], b3)))));
            z[p][4] = fmaf(h[p][4], w[24], fmaf(h[p][3], w[23], fmaf(h[p][2], w[22], fmaf(h[p][1], w[21], fmaf(h[p][0], w[20], b4)))));
        }
#pragma unroll
        for (int p = 0; p < PTS; ++p) {
#pragma unroll
            for (int j = 0; j < SIREN_HID; ++j)
                h[p][j] = __builtin_amdgcn_sinf(z[p][j]);
        }
    }

    // final linear (plain units, no sine)
    float w0 = Wfin[0], w1 = Wfin[1], w2 = Wfin[2], w3 = Wfin[3], w4 = Wfin[4];
    float bb = bfin[0];
    float o[PTS];
#pragma unroll
    for (int p = 0; p < PTS; ++p)
        o[p] = fmaf(h[p][4], w4, fmaf(h[p][3], w3, fmaf(h[p][2], w2, fmaf(h[p][1], w1, fmaf(h[p][0], w0, bb)))));

    // contiguous 32B store of the 8 outputs
    float4* op4 = (float4*)(out + PTS * i);
    op4[0] = make_float4(o[0], o[1], o[2], o[3]);
    op4[1] = make_float4(o[4], o[5], o[6], o[7]);

    // coords passthrough (second tuple element), 96B contiguous
    float4* oc4 = (float4*)(out + N + 3 * PTS * i);
#pragma unroll
    for (int k = 0; k < 6; ++k) oc4[k] = q[k];
}

extern "C" void kernel_launch(void* const* d_in, const int* in_sizes, int n_in,
                              void* d_out, int out_size, void* d_ws, size_t ws_size,
                              hipStream_t stream) {
    const float* coords = (const float*)d_in[0];
    const float* Wf     = (const float*)d_in[1];
    const float* bf     = (const float*)d_in[2];
    const float* Wh     = (const float*)d_in[3];
    const float* bh     = (const float*)d_in[4];
    const float* Wfin   = (const float*)d_in[5];
    const float* bfin   = (const float*)d_in[6];

    int N = in_sizes[0] / 3;
    float* out = (float*)d_out;
    float* ws = (float*)d_ws;

    hipLaunchKernelGGL(siren_prep, dim3(32), dim3(256), 0, stream, Wf, bf, Wh, bh, ws);

    int M = N / PTS;                     // 8 points/thread; N=524288 -> 65536 threads
    dim3 block(256);
    dim3 grid((M + 255) / 256);          // 256 blocks = 1024 waves = 1/SIMD
    hipLaunchKernelGGL(siren_fwd12, grid, block, 0, stream,
                       coords, ws, ws + SIREN_NLAYERS * 32, Wfin, bfin, out, N);
}